// Round 1
// baseline (188.743 us; speedup 1.0000x reference)
//
#include <hip/hip_runtime.h>

typedef __attribute__((ext_vector_type(8))) short short8;
typedef __attribute__((ext_vector_type(4))) float float4v;

#define BATCH 16
#define CDIM 2048
#define LDIM 64
#define BSTRIDE (CDIM * LDIM) /* 131072 elems per batch */

__device__ __forceinline__ float bf2f(unsigned short u) {
    unsigned int x = ((unsigned int)u) << 16;
    return __uint_as_float(x);
}
__device__ __forceinline__ unsigned short f2bf(float f) {
    unsigned int x = __float_as_uint(f);
    x += 0x7fffu + ((x >> 16) & 1u); // RNE
    return (unsigned short)(x >> 16);
}

__global__ void zero_out_kernel(float4v* out) {
    out[blockIdx.x * 256 + threadIdx.x] = (float4v){0.f, 0.f, 0.f, 0.f};
}

__global__ void convert_q_kernel(const float4* __restrict__ in, ushort4* __restrict__ out) {
    int i = blockIdx.x * 256 + threadIdx.x;
    float4 v = in[i];
    ushort4 o;
    o.x = f2bf(v.x); o.y = f2bf(v.y); o.z = f2bf(v.z); o.w = f2bf(v.w);
    out[i] = o;
}

// Transpose one R x C (row-major, fp32) per-batch matrix into C x R bf16.
__global__ void transpose_bf16_kernel(const float* __restrict__ in,
                                      unsigned short* __restrict__ out,
                                      int R, int C) {
    __shared__ float tile[32][33]; // +1 pad: no bank conflicts
    int b = blockIdx.z;
    const float* src = in + (size_t)b * R * C;
    unsigned short* dst = out + (size_t)b * R * C;
    int c0 = blockIdx.x * 32, r0 = blockIdx.y * 32;
    int tx = threadIdx.x & 31, ty = threadIdx.x >> 5;
#pragma unroll
    for (int p = 0; p < 4; p++)
        tile[ty + p * 8][tx] = src[(size_t)(r0 + ty + p * 8) * C + c0 + tx];
    __syncthreads();
#pragma unroll
    for (int p = 0; p < 4; p++)
        dst[(size_t)(c0 + ty + p * 8) * R + r0 + tx] = f2bf(tile[tx][ty + p * 8]);
}

// Main fused kernel.
// Grid: 256 blocks = 64 m-blocks (M_TILE=32) x 4 n-splits (512 cols each).
// Block: 1024 threads = 16 waves; wave w handles batch b=w.
// Per n-step (NT=32):
//   GEMM1 (S^T): A = Kt^T frag from kT[b][n][i] (dwordx4), B = Q frag (persistent regs)
//     -> C-frag: lane holds S[m][n] for m=lane&15(+16*msub), n = nt*16 + q*4 + r  (4 consecutive n)
//   exp -> bf16 -> Elds[b][m][n] (n-contiguous rows, pitch 40)
//   D-phase: threads 0..127 sum across b (b128 reads along n), store 1/D
//   GEMM2: A = P frag (one ds_read_b128: 8 contiguous n) * (1/D), B = V frag from vT[b][j][n] (dwordx4)
// Epilogue: fp32 atomicAdd into out (zeroed beforehand; 4 blocks/address).
__global__ __launch_bounds__(1024, 1) void attn_main_kernel(
    const unsigned short* __restrict__ qb,
    const unsigned short* __restrict__ kT,
    const unsigned short* __restrict__ vT,
    float* __restrict__ out)
{
    __shared__ unsigned short Elds[BATCH * 32 * 40]; // [b][m(32)][pitch 40] bf16 : 40 KB
    __shared__ float Dlds[32 * 36];                  // [m][pitch 36] holds 1/D : 4.5 KB

    const int tid = threadIdx.x;
    const int w = tid >> 6;   // batch
    const int lane = tid & 63;
    const int c = lane & 15;  // MFMA "lane&15" index
    const int q = lane >> 4;  // MFMA quad

    const int bx = blockIdx.x;
    const int mi = bx & 63;
    const int nj = bx >> 6;
    const int m0 = mi * 32;
    const int nbase = nj * 512;

    const unsigned short* qb_b = qb + w * BSTRIDE;
    const unsigned short* kT_b = kT + w * BSTRIDE;
    const unsigned short* vT_b = vT + w * BSTRIDE;

    // Persistent Q fragments (B-operand of GEMM1): B[k=i][col=m], lane holds 8 consecutive i.
    short8 Qf[2][2]; // [msub][ks]
#pragma unroll
    for (int ms = 0; ms < 2; ms++)
#pragma unroll
        for (int ks = 0; ks < 2; ks++)
            Qf[ms][ks] = *(const short8*)(qb_b + (m0 + ms * 16 + c) * LDIM + ks * 32 + q * 8);

    float4v acc[2][4]; // [msub][jtile] out accumulators (m x j = 32 x 64)
#pragma unroll
    for (int ms = 0; ms < 2; ms++)
#pragma unroll
        for (int jt = 0; jt < 4; jt++)
            acc[ms][jt] = (float4v){0.f, 0.f, 0.f, 0.f};

    for (int st = 0; st < 16; st++) {
        const int n0 = nbase + st * 32;

        // ---- GEMM1: S^T tiles (rows n, cols m) ----
        float4v Cf[2][2]; // [nt][msub]
#pragma unroll
        for (int nt = 0; nt < 2; nt++) {
            // A-operand: Kt^T[n][i] = kT[b][n][i]; lane&15 = n, k = ks*32 + q*8 + t
            short8 Af0 = *(const short8*)(kT_b + (n0 + nt * 16 + c) * LDIM + q * 8);
            short8 Af1 = *(const short8*)(kT_b + (n0 + nt * 16 + c) * LDIM + 32 + q * 8);
#pragma unroll
            for (int ms = 0; ms < 2; ms++) {
                float4v d = (float4v){0.f, 0.f, 0.f, 0.f};
                d = __builtin_amdgcn_mfma_f32_16x16x32_bf16(Af0, Qf[ms][0], d, 0, 0, 0);
                d = __builtin_amdgcn_mfma_f32_16x16x32_bf16(Af1, Qf[ms][1], d, 0, 0, 0);
                Cf[nt][ms] = d;
            }
        }

        // Prefetch V fragments for this step (independent of LDS phases).
        // B-operand of GEMM2: B[k=n][col=j] = vT[b][j][n]; lane&15 = j, 8 consecutive n.
        short8 Vf[4];
#pragma unroll
        for (int jt = 0; jt < 4; jt++)
            Vf[jt] = *(const short8*)(vT_b + (jt * 16 + c) * CDIM + n0 + q * 8);

        __syncthreads(); // previous iteration's Elds/Dlds consumers are done

        // exp(S/8) -> bf16 -> Elds[b][m][n]   (C-frag: col=c=m, row=q*4+r = n within nt-tile)
#pragma unroll
        for (int nt = 0; nt < 2; nt++)
#pragma unroll
            for (int ms = 0; ms < 2; ms++) {
                float4v d = Cf[nt][ms];
                ushort4 e;
                e.x = f2bf(__expf(d[0] * 0.125f));
                e.y = f2bf(__expf(d[1] * 0.125f));
                e.z = f2bf(__expf(d[2] * 0.125f));
                e.w = f2bf(__expf(d[3] * 0.125f));
                *(ushort4*)&Elds[(w * 32 + ms * 16 + c) * 40 + nt * 16 + q * 4] = e;
            }
        __syncthreads();

        // Denominator phase: 128 tasks = 32 m-rows x 4 n-segments-of-8.
        if (tid < 128) {
            int m = tid >> 2, nsg = tid & 3;
            float s[8];
#pragma unroll
            for (int t = 0; t < 8; t++) s[t] = 0.f;
#pragma unroll
            for (int b2 = 0; b2 < BATCH; b2++) {
                short8 ev = *(short8*)&Elds[(b2 * 32 + m) * 40 + nsg * 8];
#pragma unroll
                for (int t = 0; t < 8; t++) s[t] += bf2f((unsigned short)ev[t]);
            }
            float4v r0v, r1v;
#pragma unroll
            for (int t = 0; t < 4; t++) { r0v[t] = 1.f / s[t]; r1v[t] = 1.f / s[4 + t]; }
            *(float4v*)&Dlds[m * 36 + nsg * 8] = r0v;
            *(float4v*)&Dlds[m * 36 + nsg * 8 + 4] = r1v;
        }
        __syncthreads();

        // ---- GEMM2: out tile += P @ V ----
#pragma unroll
        for (int ms = 0; ms < 2; ms++) {
            // A-operand of GEMM2: lane&15 = m, k = n = q*8 + t -> one b128 read
            short8 ev = *(short8*)&Elds[(w * 32 + ms * 16 + c) * 40 + q * 8];
            float4v di0 = *(float4v*)&Dlds[(ms * 16 + c) * 36 + q * 8];
            float4v di1 = *(float4v*)&Dlds[(ms * 16 + c) * 36 + q * 8 + 4];
            short8 Pf;
#pragma unroll
            for (int t = 0; t < 4; t++)
                Pf[t] = (short)f2bf(bf2f((unsigned short)ev[t]) * di0[t]);
#pragma unroll
            for (int t = 0; t < 4; t++)
                Pf[4 + t] = (short)f2bf(bf2f((unsigned short)ev[4 + t]) * di1[t]);
#pragma unroll
            for (int jt = 0; jt < 4; jt++)
                acc[ms][jt] = __builtin_amdgcn_mfma_f32_16x16x32_bf16(Pf, Vf[jt], acc[ms][jt], 0, 0, 0);
        }
    }

    // Epilogue: C/D layout col=lane&15=j, row=q*4+r=m (within msub tile)
#pragma unroll
    for (int ms = 0; ms < 2; ms++)
#pragma unroll
        for (int jt = 0; jt < 4; jt++)
#pragma unroll
            for (int r = 0; r < 4; r++) {
                int m = m0 + ms * 16 + q * 4 + r;
                atomicAdd(&out[(w * CDIM + m) * LDIM + jt * 16 + c], acc[ms][jt][r]);
            }
}

extern "C" void kernel_launch(void* const* d_in, const int* in_sizes, int n_in,
                              void* d_out, int out_size, void* d_ws, size_t ws_size,
                              hipStream_t stream) {
    const float* q = (const float*)d_in[0];
    const float* k = (const float*)d_in[1];
    const float* v = (const float*)d_in[2];
    float* out = (float*)d_out;

    unsigned short* qb = (unsigned short*)d_ws;                 // 4 MB bf16
    unsigned short* kT = qb + (size_t)BATCH * BSTRIDE;          // 4 MB bf16, [b][n][i]
    unsigned short* vT = kT + (size_t)BATCH * BSTRIDE;          // 4 MB bf16, [b][j][n]

    // out = 16*2048*64 = 2,097,152 floats = 524,288 float4
    zero_out_kernel<<<2048, 256, 0, stream>>>((float4v*)d_out);
    convert_q_kernel<<<2048, 256, 0, stream>>>((const float4*)q, (ushort4*)qb);
    // k viewed as (64 x 2048) per batch -> kT (2048 x 64)
    transpose_bf16_kernel<<<dim3(64, 2, 16), 256, 0, stream>>>(k, kT, 64, 2048);
    // v is (2048 x 64) per batch -> vT (64 x 2048)
    transpose_bf16_kernel<<<dim3(2, 64, 16), 256, 0, stream>>>(v, vT, 2048, 64);

    attn_main_kernel<<<256, 1024, 0, stream>>>(qb, kT, vT, out);
}